// Round 1
// baseline (109.683 us; speedup 1.0000x reference)
//
#include <hip/hip_runtime.h>
#include <hip/hip_bf16.h>

#define N_NODES 50000
#define NLAT 10
#define MU 32
#define BATCH 8
#define CHUNK 2000
#define NCHUNK 25
#define ENC_BLOCKS (BATCH * NLAT * NCHUNK)     // 2000
#define TR_BLOCKS ((N_NODES + 255) / 256)      // 196
#define DT_STRIDE 16        // floats per node in transposed decoder (64B line)
#define NPB 64              // nodes per main-kernel block
#define NBR_PAD 36          // s_nbr stride: keeps [node][4k] int4-aligned (144B rows)

typedef float v2f __attribute__((ext_vector_type(2)));

static __device__ __forceinline__ v2f v2_fma(v2f a, v2f b, v2f c) {
#if __has_builtin(__builtin_elementwise_fma)
    return __builtin_elementwise_fma(a, b, c);
#else
    v2f r; r[0] = fmaf(a[0], b[0], c[0]); r[1] = fmaf(a[1], b[1], c[1]); return r;
#endif
}
static __device__ __forceinline__ v2f v2_max0(v2f a) {
#if __has_builtin(__builtin_elementwise_max)
    v2f z = {0.0f, 0.0f};
    return __builtin_elementwise_max(a, z);
#else
    v2f r; r[0] = fmaxf(a[0], 0.0f); r[1] = fmaxf(a[1], 0.0f); return r;
#endif
}

// ---------------- Kernel 1: encode partials (blocks 0..1999) + decoder
// transpose (blocks 2000..2195). Unchanged.
__global__ __launch_bounds__(256) void encode_a_transpose(
    const float* __restrict__ x, const float* __restrict__ enc_w,
    const float* __restrict__ dec,
    float* __restrict__ partial, float* __restrict__ dec_t) {
    const int bid = blockIdx.x;
    if (bid < ENC_BLOCKS) {
        const int c  = bid % NCHUNK;
        const int bi = bid / NCHUNK;
        const int b = bi / NLAT, i = bi % NLAT;
        const float4* xr = (const float4*)(x + (size_t)b * N_NODES + c * CHUNK);
        const float4* wr = (const float4*)(enc_w + (size_t)i * N_NODES + c * CHUNK);
        float part = 0.0f;
        for (int q = threadIdx.x; q < CHUNK / 4; q += 256) {
            float4 xv = xr[q], wv = wr[q];
            part += xv.x * wv.x + xv.y * wv.y + xv.z * wv.z + xv.w * wv.w;
        }
        for (int off = 32; off; off >>= 1) part += __shfl_down(part, off, 64);
        __shared__ float s[4];
        if ((threadIdx.x & 63) == 0) s[threadIdx.x >> 6] = part;
        __syncthreads();
        if (threadIdx.x == 0) partial[bid] = (s[0] + s[1]) + (s[2] + s[3]);
    } else {
        const int p = (bid - ENC_BLOCKS) * 256 + threadIdx.x;
        if (p >= N_NODES) return;
        float v[DT_STRIDE];
        #pragma unroll
        for (int i = 0; i < NLAT; ++i) v[i] = dec[(size_t)i * N_NODES + p];
        #pragma unroll
        for (int i = NLAT; i < DT_STRIDE; ++i) v[i] = 0.0f;
        float4* dst = (float4*)(dec_t + (size_t)p * DT_STRIDE);
        #pragma unroll
        for (int q = 0; q < 4; ++q)
            dst[q] = make_float4(v[4*q], v[4*q+1], v[4*q+2], v[4*q+3]);
    }
}

// ---------------- Kernel 2: fused main. Block = 64 nodes, 512 threads.
// Phase A (rebalanced): every wave g does full latent i=g PLUS a quarter
//   (2 batches) of latent 8+(g>>2) -> uniform ~1.25x critical path instead
//   of waves 0,1 doing 2 full latents.
// Phase B (latency fix): m-loop processed in blocks of 8. mcap rounded up
//   to a multiple of 8 (extra iterations have win==relu(<=0)==0, exact
//   no-op). Per 8-block: 2x int4 LDS index read + 8 independent float2
//   gathers in flight -> one L2 latency amortized over 8 gathers instead
//   of a vmcnt(0) round-trip per m.
__global__ __launch_bounds__(512, 4) void nrbs_main_kernel(
    const float* __restrict__ dec_t,    // [N, 16]
    const float* __restrict__ bw,       // [n, n, N]
    const int*   __restrict__ nbr,      // [N, MU]
    const float* __restrict__ partial,  // [B*n, NCHUNK]
    const float* __restrict__ enc_b,    // [n]
    float*       __restrict__ out) {    // [B, N]
    __shared__ float s_enc[BATCH * NLAT];
    __shared__ float s_inv[NLAT][NPB][BATCH];   // 20 KB
    __shared__ int   s_tm[NPB];
    __shared__ int   s_nbr[NPB][NBR_PAD];       // 9.2 KB, int4-aligned rows
    const int tid   = threadIdx.x;
    const int node0 = blockIdx.x * NPB;

    // prologue: finish encode reduction; init tmax; stage neighbour lists
    if (tid < BATCH * NLAT) {
        float s = 0.0f;
        #pragma unroll
        for (int c = 0; c < NCHUNK; ++c) s += partial[tid * NCHUNK + c];
        s_enc[tid] = s + enc_b[tid % NLAT];
    }
    if (tid < NPB) s_tm[tid] = 0;
    {
        const int nodeS = tid >> 3, ch = tid & 7;     // 512 int4 chunks
        int4 v = make_int4(0, 0, 0, 0);
        if (node0 + nodeS < N_NODES)
            v = ((const int4*)(nbr + (size_t)(node0 + nodeS) * MU))[ch];
        *(int4*)&s_nbr[nodeS][ch * 4] = v;            // words 0..31 of 36
    }
    __syncthreads();

    // ---- Phase A: coalesced bw loads, inv/tmax -> LDS (balanced)
    {
        const int g    = tid >> 6;       // wave id 0..7
        const int lane = tid & 63;       // node
        const int p    = node0 + lane;
        if (p < N_NODES) {
            float tloc = 0.0f;
            // full latent i = g, all 8 batches
            {
                const int i = g;
                float bwv[NLAT];
                #pragma unroll
                for (int k = 0; k < NLAT; ++k)
                    bwv[k] = bw[((size_t)(i * NLAT + k)) * N_NODES + p];
                float invv[BATCH];
                #pragma unroll
                for (int b = 0; b < BATCH; ++b) {
                    float z = 0.0f;
                    #pragma unroll
                    for (int k = 0; k < NLAT; ++k)
                        z = fmaf(s_enc[b * NLAT + k], bwv[k], z);
                    const float sg = 1.0f / (1.0f + __expf(-z));
                    const float t  = sg * (float)MU;
                    tloc = fmaxf(tloc, t);
                    invv[b] = __builtin_amdgcn_rcpf(t * t);
                }
                float4* dst = (float4*)&s_inv[i][lane][0];
                dst[0] = make_float4(invv[0], invv[1], invv[2], invv[3]);
                dst[1] = make_float4(invv[4], invv[5], invv[6], invv[7]);
            }
            // quarter latent: i = 8 + (g>>2), batches b0..b0+1
            // (bw rows duplicated across 4 waves -> L1 hits, negligible)
            {
                const int i  = 8 + (g >> 2);
                const int b0 = (g & 3) * 2;
                float bwv[NLAT];
                #pragma unroll
                for (int k = 0; k < NLAT; ++k)
                    bwv[k] = bw[((size_t)(i * NLAT + k)) * N_NODES + p];
                float iv2[2];
                #pragma unroll
                for (int h = 0; h < 2; ++h) {
                    float z = 0.0f;
                    #pragma unroll
                    for (int k = 0; k < NLAT; ++k)
                        z = fmaf(s_enc[(b0 + h) * NLAT + k], bwv[k], z);
                    const float sg = 1.0f / (1.0f + __expf(-z));
                    const float t  = sg * (float)MU;
                    tloc = fmaxf(tloc, t);
                    iv2[h] = __builtin_amdgcn_rcpf(t * t);
                }
                *(float2*)&s_inv[i][lane][b0] = make_float2(iv2[0], iv2[1]);
            }
            atomicMax(&s_tm[lane], __float_as_int(tloc));  // t>0: bits ordered
        }
    }
    __syncthreads();

    // ---- Phase B: thread = (node, ipair); pairs 0..4 cover i = 0..9
    const int node  = tid >> 3;          // 0..63
    const int ipair = tid & 7;           // 0..7 (0..4 active)
    const int p     = node0 + node;
    const int i0    = 2 * ipair;
    const bool act  = (ipair < 5) && (p < N_NODES);

    v2f inv2[2][4], asum[2][4], ssum[2][4];
    #pragma unroll
    for (int ii = 0; ii < 2; ++ii)
        #pragma unroll
        for (int b2 = 0; b2 < 4; ++b2) {
            inv2[ii][b2] = (v2f){0.0f, 0.0f};
            asum[ii][b2] = (v2f){0.0f, 0.0f};
            ssum[ii][b2] = (v2f){0.0f, 0.0f};
        }
    int mcap = 0;
    if (act) {
        #pragma unroll
        for (int ii = 0; ii < 2; ++ii) {
            const float4* iv = (const float4*)&s_inv[i0 + ii][node][0];
            const float4 a = iv[0], c = iv[1];
            inv2[ii][0] = (v2f){a.x, a.y}; inv2[ii][1] = (v2f){a.z, a.w};
            inv2[ii][2] = (v2f){c.x, c.y}; inv2[ii][3] = (v2f){c.z, c.w};
        }
        mcap = min(MU, (int)__int_as_float(s_tm[node]) + 1);
    }
    // round up to multiple of 8: for m >= mcap, m >= t for ALL (i,b), so
    // win = relu(1 - m^2/t^2) = 0 -> extra iterations are exact no-ops.
    const int mcap8 = (mcap + 7) & ~7;   // 0, 8, 16, 24, or 32

    const v2f one = {1.0f, 1.0f};
    const float* __restrict__ bp = dec_t + i0;

    auto step = [&](int m, v2f g2) {
        const float m2f = (float)(m * m);
        const v2f nm2 = {-m2f, -m2f};
        #pragma unroll
        for (int ii = 0; ii < 2; ++ii) {
            const v2f gg = {g2[ii], g2[ii]};
            #pragma unroll
            for (int b2 = 0; b2 < 4; ++b2) {
                const v2f win = v2_max0(v2_fma(nm2, inv2[ii][b2], one));
                ssum[ii][b2] += win;
                asum[ii][b2] = v2_fma(gg, win, asum[ii][b2]);
            }
        }
    };

    for (int mb = 0; mb < mcap8; mb += 8) {
        // 8 neighbour indices via two aligned int4 LDS reads
        const int4 na = *(const int4*)&s_nbr[node][mb];
        const int4 nb = *(const int4*)&s_nbr[node][mb + 4];
        // 8 independent gathers in flight (compiler interleaves vmcnt waits)
        const v2f g0 = *(const v2f*)(bp + (size_t)na.x * DT_STRIDE);
        const v2f g1 = *(const v2f*)(bp + (size_t)na.y * DT_STRIDE);
        const v2f g2 = *(const v2f*)(bp + (size_t)na.z * DT_STRIDE);
        const v2f g3 = *(const v2f*)(bp + (size_t)na.w * DT_STRIDE);
        const v2f g4 = *(const v2f*)(bp + (size_t)nb.x * DT_STRIDE);
        const v2f g5 = *(const v2f*)(bp + (size_t)nb.y * DT_STRIDE);
        const v2f g6 = *(const v2f*)(bp + (size_t)nb.z * DT_STRIDE);
        const v2f g7 = *(const v2f*)(bp + (size_t)nb.w * DT_STRIDE);
        step(mb + 0, g0); step(mb + 1, g1);
        step(mb + 2, g2); step(mb + 3, g3);
        step(mb + 4, g4); step(mb + 5, g5);
        step(mb + 6, g6); step(mb + 7, g7);
    }

    // epilogue: r[b] = this lane's 2-latent contribution; butterfly over the
    // 8-lane ipair group so every lane holds the full sum for each b.
    float r[BATCH];
    #pragma unroll
    for (int b2 = 0; b2 < 4; ++b2)
        #pragma unroll
        for (int h = 0; h < 2; ++h) {
            const int b = 2 * b2 + h;
            r[b] = act ? s_enc[b * NLAT + i0]     * asum[0][b2][h] *
                             __builtin_amdgcn_rcpf(ssum[0][b2][h]) +
                         s_enc[b * NLAT + i0 + 1] * asum[1][b2][h] *
                             __builtin_amdgcn_rcpf(ssum[1][b2][h])
                       : 0.0f;
        }
    #pragma unroll
    for (int mask = 1; mask < 8; mask <<= 1)
        #pragma unroll
        for (int b = 0; b < BATCH; ++b)
            r[b] += __shfl_xor(r[b], mask, 8);

    if (p < N_NODES)
        out[(size_t)ipair * N_NODES + p] = r[ipair];   // lane ipair -> batch ipair
}

extern "C" void kernel_launch(void* const* d_in, const int* in_sizes, int n_in,
                              void* d_out, int out_size, void* d_ws, size_t ws_size,
                              hipStream_t stream) {
    const float* x       = (const float*)d_in[0];   // [B, N]
    const float* enc_w   = (const float*)d_in[1];   // [n, N]
    const float* enc_b   = (const float*)d_in[2];   // [n]
    const float* decoder = (const float*)d_in[3];   // [n, N]
    const float* bwl     = (const float*)d_in[4];   // [n, n, N]
    const int*   nbr     = (const int*)d_in[5];     // [N, MU]
    float* out = (float*)d_out;                     // [B, N]

    float* partial = (float*)((char*)d_ws + 1024);   // 2000 floats
    float* dec_t   = (float*)((char*)d_ws + 65536);  // 3.2 MB

    encode_a_transpose<<<ENC_BLOCKS + TR_BLOCKS, 256, 0, stream>>>(
        x, enc_w, decoder, partial, dec_t);

    const int blocks = (N_NODES + NPB - 1) / NPB;   // 782
    nrbs_main_kernel<<<blocks, 512, 0, stream>>>(
        dec_t, bwl, nbr, partial, enc_b, out);
}

// Round 2
// 106.375 us; speedup vs baseline: 1.0311x; 1.0311x over previous
//
#include <hip/hip_runtime.h>
#include <hip/hip_bf16.h>

#define N_NODES 50000
#define NLAT 10
#define MU 32
#define BATCH 8
#define CHUNK 2000
#define NCHUNK 25
#define ENC_BLOCKS (BATCH * NLAT * NCHUNK)     // 2000
#define TR_BLOCKS ((N_NODES + 255) / 256)      // 196
#define DT_STRIDE 16        // floats per node in transposed decoder (64B line)
#define NPB 64              // nodes per main-kernel block
#define NBR_PAD 36          // s_nbr stride: keeps [node][4k] int4-aligned (144B rows)

typedef float v2f __attribute__((ext_vector_type(2)));

static __device__ __forceinline__ v2f v2_fma(v2f a, v2f b, v2f c) {
#if __has_builtin(__builtin_elementwise_fma)
    return __builtin_elementwise_fma(a, b, c);
#else
    v2f r; r[0] = fmaf(a[0], b[0], c[0]); r[1] = fmaf(a[1], b[1], c[1]); return r;
#endif
}
static __device__ __forceinline__ v2f v2_max0(v2f a) {
#if __has_builtin(__builtin_elementwise_max)
    v2f z = {0.0f, 0.0f};
    return __builtin_elementwise_max(a, z);
#else
    v2f r; r[0] = fmaxf(a[0], 0.0f); r[1] = fmaxf(a[1], 0.0f); return r;
#endif
}

// ---------------- Kernel 1: encode partials (blocks 0..1999) + decoder
// transpose (blocks 2000..2195). Unchanged.
__global__ __launch_bounds__(256) void encode_a_transpose(
    const float* __restrict__ x, const float* __restrict__ enc_w,
    const float* __restrict__ dec,
    float* __restrict__ partial, float* __restrict__ dec_t) {
    const int bid = blockIdx.x;
    if (bid < ENC_BLOCKS) {
        const int c  = bid % NCHUNK;
        const int bi = bid / NCHUNK;
        const int b = bi / NLAT, i = bi % NLAT;
        const float4* xr = (const float4*)(x + (size_t)b * N_NODES + c * CHUNK);
        const float4* wr = (const float4*)(enc_w + (size_t)i * N_NODES + c * CHUNK);
        float part = 0.0f;
        for (int q = threadIdx.x; q < CHUNK / 4; q += 256) {
            float4 xv = xr[q], wv = wr[q];
            part += xv.x * wv.x + xv.y * wv.y + xv.z * wv.z + xv.w * wv.w;
        }
        for (int off = 32; off; off >>= 1) part += __shfl_down(part, off, 64);
        __shared__ float s[4];
        if ((threadIdx.x & 63) == 0) s[threadIdx.x >> 6] = part;
        __syncthreads();
        if (threadIdx.x == 0) partial[bid] = (s[0] + s[1]) + (s[2] + s[3]);
    } else {
        const int p = (bid - ENC_BLOCKS) * 256 + threadIdx.x;
        if (p >= N_NODES) return;
        float v[DT_STRIDE];
        #pragma unroll
        for (int i = 0; i < NLAT; ++i) v[i] = dec[(size_t)i * N_NODES + p];
        #pragma unroll
        for (int i = NLAT; i < DT_STRIDE; ++i) v[i] = 0.0f;
        float4* dst = (float4*)(dec_t + (size_t)p * DT_STRIDE);
        #pragma unroll
        for (int q = 0; q < 4; ++q)
            dst[q] = make_float4(v[4*q], v[4*q+1], v[4*q+2], v[4*q+3]);
    }
}

// ---------------- Kernel 2: fused main. Block = 64 nodes, 512 threads.
// OCCUPANCY: __launch_bounds__(512, 6) caps VGPR at 85 -> 6 waves/SIMD ->
//   24 waves/CU -> 3 blocks/CU (LDS 30KB x 3 = 90KB <= 160KB). 768 of 782
//   blocks co-resident: the grid runs in ~one pass instead of two (512+270
//   at the previous 2 blocks/CU), and Phase-A HBM bursts of one block hide
//   under Phase-B VALU of co-resident blocks.
// Phase B: m-loop in blocks of 4 (4 gathers in flight = 8 VGPRs, fits the
//   85-VGPR cap; mcap rounds to x4 not x8 -> ~20 steps instead of ~24,
//   exact: padded m >= t has win = relu(<=0) = 0).
__global__ __launch_bounds__(512, 6) void nrbs_main_kernel(
    const float* __restrict__ dec_t,    // [N, 16]
    const float* __restrict__ bw,       // [n, n, N]
    const int*   __restrict__ nbr,      // [N, MU]
    const float* __restrict__ partial,  // [B*n, NCHUNK]
    const float* __restrict__ enc_b,    // [n]
    float*       __restrict__ out) {    // [B, N]
    __shared__ float s_enc[BATCH * NLAT];
    __shared__ float s_inv[NLAT][NPB][BATCH];   // 20 KB
    __shared__ int   s_tm[NPB];
    __shared__ int   s_nbr[NPB][NBR_PAD];       // 9.2 KB, int4-aligned rows
    const int tid   = threadIdx.x;
    const int node0 = blockIdx.x * NPB;

    // prologue: finish encode reduction; init tmax; stage neighbour lists
    if (tid < BATCH * NLAT) {
        float s = 0.0f;
        #pragma unroll
        for (int c = 0; c < NCHUNK; ++c) s += partial[tid * NCHUNK + c];
        s_enc[tid] = s + enc_b[tid % NLAT];
    }
    if (tid < NPB) s_tm[tid] = 0;
    {
        const int nodeS = tid >> 3, ch = tid & 7;     // 512 int4 chunks
        int4 v = make_int4(0, 0, 0, 0);
        if (node0 + nodeS < N_NODES)
            v = ((const int4*)(nbr + (size_t)(node0 + nodeS) * MU))[ch];
        *(int4*)&s_nbr[nodeS][ch * 4] = v;            // words 0..31 of 36
    }
    __syncthreads();

    // ---- Phase A: coalesced bw loads, inv/tmax -> LDS (balanced)
    {
        const int g    = tid >> 6;       // wave id 0..7
        const int lane = tid & 63;       // node
        const int p    = node0 + lane;
        if (p < N_NODES) {
            float tloc = 0.0f;
            // full latent i = g, all 8 batches
            {
                const int i = g;
                float bwv[NLAT];
                #pragma unroll
                for (int k = 0; k < NLAT; ++k)
                    bwv[k] = bw[((size_t)(i * NLAT + k)) * N_NODES + p];
                float invv[BATCH];
                #pragma unroll
                for (int b = 0; b < BATCH; ++b) {
                    float z = 0.0f;
                    #pragma unroll
                    for (int k = 0; k < NLAT; ++k)
                        z = fmaf(s_enc[b * NLAT + k], bwv[k], z);
                    const float sg = 1.0f / (1.0f + __expf(-z));
                    const float t  = sg * (float)MU;
                    tloc = fmaxf(tloc, t);
                    invv[b] = __builtin_amdgcn_rcpf(t * t);
                }
                float4* dst = (float4*)&s_inv[i][lane][0];
                dst[0] = make_float4(invv[0], invv[1], invv[2], invv[3]);
                dst[1] = make_float4(invv[4], invv[5], invv[6], invv[7]);
            }
            // quarter latent: i = 8 + (g>>2), batches b0..b0+1
            // (bw rows duplicated across 4 waves -> L1 hits, negligible)
            {
                const int i  = 8 + (g >> 2);
                const int b0 = (g & 3) * 2;
                float bwv[NLAT];
                #pragma unroll
                for (int k = 0; k < NLAT; ++k)
                    bwv[k] = bw[((size_t)(i * NLAT + k)) * N_NODES + p];
                float iv2[2];
                #pragma unroll
                for (int h = 0; h < 2; ++h) {
                    float z = 0.0f;
                    #pragma unroll
                    for (int k = 0; k < NLAT; ++k)
                        z = fmaf(s_enc[(b0 + h) * NLAT + k], bwv[k], z);
                    const float sg = 1.0f / (1.0f + __expf(-z));
                    const float t  = sg * (float)MU;
                    tloc = fmaxf(tloc, t);
                    iv2[h] = __builtin_amdgcn_rcpf(t * t);
                }
                *(float2*)&s_inv[i][lane][b0] = make_float2(iv2[0], iv2[1]);
            }
            atomicMax(&s_tm[lane], __float_as_int(tloc));  // t>0: bits ordered
        }
    }
    __syncthreads();

    // ---- Phase B: thread = (node, ipair); pairs 0..4 cover i = 0..9
    const int node  = tid >> 3;          // 0..63
    const int ipair = tid & 7;           // 0..7 (0..4 active)
    const int p     = node0 + node;
    const int i0    = 2 * ipair;
    const bool act  = (ipair < 5) && (p < N_NODES);

    v2f inv2[2][4], asum[2][4], ssum[2][4];
    #pragma unroll
    for (int ii = 0; ii < 2; ++ii)
        #pragma unroll
        for (int b2 = 0; b2 < 4; ++b2) {
            inv2[ii][b2] = (v2f){0.0f, 0.0f};
            asum[ii][b2] = (v2f){0.0f, 0.0f};
            ssum[ii][b2] = (v2f){0.0f, 0.0f};
        }
    int mcap = 0;
    if (act) {
        #pragma unroll
        for (int ii = 0; ii < 2; ++ii) {
            const float4* iv = (const float4*)&s_inv[i0 + ii][node][0];
            const float4 a = iv[0], c = iv[1];
            inv2[ii][0] = (v2f){a.x, a.y}; inv2[ii][1] = (v2f){a.z, a.w};
            inv2[ii][2] = (v2f){c.x, c.y}; inv2[ii][3] = (v2f){c.z, c.w};
        }
        mcap = min(MU, (int)__int_as_float(s_tm[node]) + 1);
    }
    // round up to multiple of 4: for m >= mcap, m >= t for ALL (i,b), so
    // win = relu(1 - m^2/t^2) = 0 -> extra iterations are exact no-ops.
    const int mcap4 = (mcap + 3) & ~3;   // 0,4,...,32

    const v2f one = {1.0f, 1.0f};
    const float* __restrict__ bp = dec_t + i0;

    auto step = [&](int m, v2f g2) {
        const float m2f = (float)(m * m);
        const v2f nm2 = {-m2f, -m2f};
        #pragma unroll
        for (int ii = 0; ii < 2; ++ii) {
            const v2f gg = {g2[ii], g2[ii]};
            #pragma unroll
            for (int b2 = 0; b2 < 4; ++b2) {
                const v2f win = v2_max0(v2_fma(nm2, inv2[ii][b2], one));
                ssum[ii][b2] += win;
                asum[ii][b2] = v2_fma(gg, win, asum[ii][b2]);
            }
        }
    };

    for (int mb = 0; mb < mcap4; mb += 4) {
        // 4 neighbour indices via one aligned int4 LDS read (broadcast
        // within each 8-lane node group)
        const int4 na = *(const int4*)&s_nbr[node][mb];
        // 4 independent gathers in flight (compiler interleaves vmcnt waits)
        const v2f g0 = *(const v2f*)(bp + (size_t)na.x * DT_STRIDE);
        const v2f g1 = *(const v2f*)(bp + (size_t)na.y * DT_STRIDE);
        const v2f g2 = *(const v2f*)(bp + (size_t)na.z * DT_STRIDE);
        const v2f g3 = *(const v2f*)(bp + (size_t)na.w * DT_STRIDE);
        step(mb + 0, g0); step(mb + 1, g1);
        step(mb + 2, g2); step(mb + 3, g3);
    }

    // epilogue: r[b] = this lane's 2-latent contribution; butterfly over the
    // 8-lane ipair group so every lane holds the full sum for each b.
    float r[BATCH];
    #pragma unroll
    for (int b2 = 0; b2 < 4; ++b2)
        #pragma unroll
        for (int h = 0; h < 2; ++h) {
            const int b = 2 * b2 + h;
            r[b] = act ? s_enc[b * NLAT + i0]     * asum[0][b2][h] *
                             __builtin_amdgcn_rcpf(ssum[0][b2][h]) +
                         s_enc[b * NLAT + i0 + 1] * asum[1][b2][h] *
                             __builtin_amdgcn_rcpf(ssum[1][b2][h])
                       : 0.0f;
        }
    #pragma unroll
    for (int mask = 1; mask < 8; mask <<= 1)
        #pragma unroll
        for (int b = 0; b < BATCH; ++b)
            r[b] += __shfl_xor(r[b], mask, 8);

    if (p < N_NODES)
        out[(size_t)ipair * N_NODES + p] = r[ipair];   // lane ipair -> batch ipair
}

extern "C" void kernel_launch(void* const* d_in, const int* in_sizes, int n_in,
                              void* d_out, int out_size, void* d_ws, size_t ws_size,
                              hipStream_t stream) {
    const float* x       = (const float*)d_in[0];   // [B, N]
    const float* enc_w   = (const float*)d_in[1];   // [n, N]
    const float* enc_b   = (const float*)d_in[2];   // [n]
    const float* decoder = (const float*)d_in[3];   // [n, N]
    const float* bwl     = (const float*)d_in[4];   // [n, n, N]
    const int*   nbr     = (const int*)d_in[5];     // [N, MU]
    float* out = (float*)d_out;                     // [B, N]

    float* partial = (float*)((char*)d_ws + 1024);   // 2000 floats
    float* dec_t   = (float*)((char*)d_ws + 65536);  // 3.2 MB

    encode_a_transpose<<<ENC_BLOCKS + TR_BLOCKS, 256, 0, stream>>>(
        x, enc_w, decoder, partial, dec_t);

    const int blocks = (N_NODES + NPB - 1) / NPB;   // 782
    nrbs_main_kernel<<<blocks, 512, 0, stream>>>(
        dec_t, bwl, nbr, partial, enc_b, out);
}